// Round 2
// baseline (1625.949 us; speedup 1.0000x reference)
//
#include <hip/hip_runtime.h>
#include <hip/hip_bf16.h>

// ---------------- shapes ----------------
#define Bdim 2
#define Tdim 1024
#define DMODEL 2048
#define DSTATE 64
#define HEADDIM 64
#define DCONV 4
#define DINNER 4096
#define NHEADS 64
#define CONVDIM 4224           // DINNER + 2*DSTATE
#define DINPROJ 8384           // 2*DINNER + 2*DSTATE + NHEADS
#define NPAD 8448              // DINPROJ padded to multiple of 128
#define MROWS (Bdim*Tdim)      // 2048

typedef __attribute__((ext_vector_type(8))) short bf16x8;
typedef __attribute__((ext_vector_type(4))) float f32x4;

__device__ __forceinline__ unsigned short f2bf(float f) {
    unsigned int x = __builtin_bit_cast(unsigned int, f);
    x += 0x7fffu + ((x >> 16) & 1u);   // RNE
    return (unsigned short)(x >> 16);
}
__device__ __forceinline__ float siluf(float v) {
    return v / (1.f + expf(-v));
}

// ---------------- fp32 -> bf16 weight convert (with zero row pad) ------------
__global__ __launch_bounds__(256) void cvtpad_k(const float* __restrict__ src,
                                                unsigned short* __restrict__ dst,
                                                int src_rows, int K, int total) {
    int idx = blockIdx.x * 256 + threadIdx.x;
    if (idx >= total) return;
    int row = idx / K;
    dst[idx] = (row < src_rows) ? f2bf(src[idx]) : (unsigned short)0;
}

// ---------------- LayerNorm: x fp32 -> u bf16 ----------------
__global__ __launch_bounds__(256) void layernorm_k(const float* __restrict__ x,
                                                   const float* __restrict__ w,
                                                   const float* __restrict__ b,
                                                   unsigned short* __restrict__ u) {
    int row = blockIdx.x;
    const float* xr = x + (size_t)row * DMODEL;
    float v[8];
    float s = 0.f, s2 = 0.f;
#pragma unroll
    for (int i = 0; i < 8; ++i) {
        v[i] = xr[threadIdx.x + 256 * i];
        s += v[i]; s2 += v[i] * v[i];
    }
#pragma unroll
    for (int off = 32; off; off >>= 1) { s += __shfl_down(s, off); s2 += __shfl_down(s2, off); }
    __shared__ float rs[4], rs2[4];
    if ((threadIdx.x & 63) == 0) { rs[threadIdx.x >> 6] = s; rs2[threadIdx.x >> 6] = s2; }
    __syncthreads();
    s = rs[0] + rs[1] + rs[2] + rs[3];
    s2 = rs2[0] + rs2[1] + rs2[2] + rs2[3];
    float mu = s * (1.f / DMODEL);
    float var = s2 * (1.f / DMODEL) - mu * mu;
    float inv = rsqrtf(var + 1e-5f);
#pragma unroll
    for (int i = 0; i < 8; ++i) {
        int c = threadIdx.x + 256 * i;
        float o = (v[i] - mu) * inv * w[c] + b[c];
        u[(size_t)row * DMODEL + c] = f2bf(o);
    }
}

// ---------------- bf16 GEMM, B given as (N x K) row-major ("B^T" form) -------
// C[m][n] = sum_k A[m][k]*Bw[n][k].  A has row stride lda (elements).
// EPI=0: store fp32 (ld=N). EPI=1: fp32 out = resid + acc.
template <int EPI>
__global__ __launch_bounds__(256) void gemm_bt(const unsigned short* __restrict__ A,
                                               const unsigned short* __restrict__ Bw,
                                               float* __restrict__ Cout,
                                               const float* __restrict__ resid,
                                               int M, int N, int K, int lda) {
    const int m0 = blockIdx.y * 128, n0 = blockIdx.x * 128;
    __shared__ unsigned short As[128][40];
    __shared__ unsigned short Bs[128][40];
    const int tid = threadIdx.x;
    const int lane = tid & 63, w = tid >> 6;
    const int wm = (w >> 1) * 64, wn = (w & 1) * 64;
    const int r0 = tid >> 2, c0 = (tid & 3) * 8, r1 = r0 + 64;
    const int row16 = lane & 15, quad = lane >> 4, kq = quad * 8;

    f32x4 acc[4][4];
#pragma unroll
    for (int i = 0; i < 4; ++i)
#pragma unroll
        for (int j = 0; j < 4; ++j) acc[i][j] = (f32x4){0.f, 0.f, 0.f, 0.f};

    for (int k0 = 0; k0 < K; k0 += 32) {
        uint4 a0 = *(const uint4*)(A + (size_t)(m0 + r0) * lda + k0 + c0);
        uint4 a1 = *(const uint4*)(A + (size_t)(m0 + r1) * lda + k0 + c0);
        uint4 b0 = *(const uint4*)(Bw + (size_t)(n0 + r0) * K + k0 + c0);
        uint4 b1 = *(const uint4*)(Bw + (size_t)(n0 + r1) * K + k0 + c0);
        __syncthreads();
        *(uint4*)&As[r0][c0] = a0;
        *(uint4*)&As[r1][c0] = a1;
        *(uint4*)&Bs[r0][c0] = b0;
        *(uint4*)&Bs[r1][c0] = b1;
        __syncthreads();
        bf16x8 af[4], bfr[4];
#pragma unroll
        for (int i = 0; i < 4; ++i) af[i] = *(const bf16x8*)&As[wm + i * 16 + row16][kq];
#pragma unroll
        for (int j = 0; j < 4; ++j) bfr[j] = *(const bf16x8*)&Bs[wn + j * 16 + row16][kq];
#pragma unroll
        for (int i = 0; i < 4; ++i)
#pragma unroll
            for (int j = 0; j < 4; ++j)
                acc[i][j] = __builtin_amdgcn_mfma_f32_16x16x32_bf16(af[i], bfr[j], acc[i][j], 0, 0, 0);
    }

#pragma unroll
    for (int i = 0; i < 4; ++i)
#pragma unroll
        for (int j = 0; j < 4; ++j)
#pragma unroll
            for (int r = 0; r < 4; ++r) {
                int m = m0 + wm + i * 16 + quad * 4 + r;
                int n = n0 + wn + j * 16 + row16;
                float v = acc[i][j][r];
                if (EPI == 0)
                    Cout[(size_t)m * N + n] = v;
                else
                    Cout[(size_t)m * N + n] = resid[(size_t)m * N + n] + v;
            }
}

// ---------------- causal depthwise conv(4) + SiLU (fp32 in/out) --------------
__global__ __launch_bounds__(256) void conv_k(const float* __restrict__ zx,
                                              const float* __restrict__ cw,
                                              const float* __restrict__ cb,
                                              float* __restrict__ xin,
                                              float* __restrict__ bcf) {
    int idx = blockIdx.x * 256 + threadIdx.x;
    if (idx >= MROWS * CONVDIM) return;
    int c = idx % CONVDIM;
    int bt = idx / CONVDIM;
    int t = bt & (Tdim - 1);
    const float* base = zx + (size_t)bt * NPAD + DINNER + c;
    float acc = cb[c];
#pragma unroll
    for (int kk = 0; kk < DCONV; ++kk) {
        int tt = t - 3 + kk;
        if (tt >= 0) acc += base[(long)(kk - 3) * NPAD] * cw[c * 4 + kk];
    }
    float s = siluf(acc);
    if (c < DINNER) xin[(size_t)bt * DINNER + c] = s;
    else            bcf[(size_t)bt * 128 + (c - DINNER)] = s;
}

// ---------------- dt = softplus(dt_raw + bias); dA = exp(dt*A) ----------------
__global__ __launch_bounds__(256) void dt_k(const float* __restrict__ zx,
                                            const float* __restrict__ dt_bias,
                                            const float* __restrict__ A_log,
                                            float* __restrict__ dtf,
                                            float* __restrict__ daf) {
    int idx = blockIdx.x * 256 + threadIdx.x;
    if (idx >= MROWS * NHEADS) return;
    int h = idx & 63;
    int bt = idx >> 6;
    float raw = zx[(size_t)bt * NPAD + (DINNER + CONVDIM) + h] + dt_bias[h];
    float dtv = (raw > 20.f) ? raw : log1pf(expf(raw));
    float A = -expf(A_log[h]);
    dtf[idx] = dtv;
    daf[idx] = expf(dtv * A);
}

// ---------------- sequential SSM scan: one wave per (b,h), lane = p ----------
// In-place: reads xin[t], writes y[t] to the same slot (each slot touched
// exactly once, at its own timestep -> race-free).
__global__ __launch_bounds__(64) void scan_k(float* __restrict__ xy,
                                             const float* __restrict__ bcf,
                                             const float* __restrict__ dtf,
                                             const float* __restrict__ daf,
                                             const float* __restrict__ Dp) {
    int bh = blockIdx.x;
    int h = bh & 63, b = bh >> 6;
    int p = threadIdx.x;
    float hs[64];
#pragma unroll
    for (int n = 0; n < 64; ++n) hs[n] = 0.f;
    float Dh = Dp[h];
    for (int t = 0; t < Tdim; ++t) {
        int bt = b * Tdim + t;
        float dAv = daf[bt * 64 + h];
        float dtv = dtf[bt * 64 + h];
        float xv = xy[(size_t)bt * DINNER + h * 64 + p];
        float dtx = dtv * xv;
        const float* __restrict__ Br = bcf + (size_t)bt * 128;
        float y = 0.f;
#pragma unroll
        for (int n = 0; n < 64; ++n) {
            hs[n] = hs[n] * dAv + dtx * Br[n];
            y += hs[n] * Br[64 + n];
        }
        y += Dh * xv;
        xy[(size_t)bt * DINNER + h * 64 + p] = y;
    }
}

// ---------------- y * silu(z), RMSNorm, -> bf16 (strided dest) ---------------
__global__ __launch_bounds__(256) void gate_k(const float* __restrict__ ybf,
                                              const float* __restrict__ zx,
                                              const float* __restrict__ nw,
                                              unsigned short* __restrict__ yg,
                                              int ldyg) {
    int row = blockIdx.x;
    float tv[16];
    float s2 = 0.f;
#pragma unroll
    for (int i = 0; i < 16; ++i) {
        int c = threadIdx.x + 256 * i;
        float y = ybf[(size_t)row * DINNER + c];
        float z = zx[(size_t)row * NPAD + c];
        float tvi = y * siluf(z);
        tv[i] = tvi;
        s2 += tvi * tvi;
    }
#pragma unroll
    for (int off = 32; off; off >>= 1) s2 += __shfl_down(s2, off);
    __shared__ float rs[4];
    if ((threadIdx.x & 63) == 0) rs[threadIdx.x >> 6] = s2;
    __syncthreads();
    s2 = rs[0] + rs[1] + rs[2] + rs[3];
    float scale = rsqrtf(s2 * (1.f / DINNER) + 1e-5f);
#pragma unroll
    for (int i = 0; i < 16; ++i) {
        int c = threadIdx.x + 256 * i;
        yg[(size_t)row * ldyg + c] = f2bf(tv[i] * scale * nw[c]);
    }
}

// ---------------- launch ----------------
extern "C" void kernel_launch(void* const* d_in, const int* in_sizes, int n_in,
                              void* d_out, int out_size, void* d_ws, size_t ws_size,
                              hipStream_t stream) {
    const float* x        = (const float*)d_in[0];
    const float* ln_w     = (const float*)d_in[1];
    const float* ln_b     = (const float*)d_in[2];
    const float* in_proj  = (const float*)d_in[3];
    const float* conv_w   = (const float*)d_in[4];
    const float* conv_b   = (const float*)d_in[5];
    const float* dt_bias  = (const float*)d_in[6];
    const float* A_log    = (const float*)d_in[7];
    const float* Dp       = (const float*)d_in[8];
    const float* norm_w   = (const float*)d_in[9];
    const float* out_proj = (const float*)d_in[10];
    float* out = (float*)d_out;
    char* ws = (char*)d_ws;

    // ---- workspace layout (total 128,974,848 B) ----
    // [0, 69206016)            zx fp32 (2048 x 8448)  — z cols live until gate;
    //                          cols >= 4096 dead after conv/dt -> yg packs there
    // [69206016, 85983232)     wout bf16 (2048 x 4096)
    // [85983232, 120586240)    win bf16 (8448 x 2048); after GEMM1 reused as
    //                          xin/y fp32 (2048 x 4096) = 33,554,432 B
    // [120586240, 128974848)   ubf bf16 (2048 x 2048); after GEMM1 reused as
    //                          bcf (1 MB) + dtf (0.5 MB) + daf (0.5 MB)
    float*          zx   = (float*)(ws + 0);
    unsigned short* wout = (unsigned short*)(ws + 69206016);
    unsigned short* win  = (unsigned short*)(ws + 85983232);
    unsigned short* ubf  = (unsigned short*)(ws + 120586240);
    float*          xin  = (float*)(ws + 85983232);            // reuses win
    float*          bcf  = (float*)(ws + 120586240);           // reuses ubf
    float*          dtf  = (float*)(ws + 121634816);
    float*          daf  = (float*)(ws + 122159104);
    // yg bf16 packed into dead columns of zx: row m at shorts offset m*16896+8192
    unsigned short* yg   = (unsigned short*)zx + 8192;
    const int       ldyg = 16896;   // 8448 floats = 16896 shorts per row

    // 1) weights -> bf16 (in_proj padded 8384 -> 8448 rows)
    cvtpad_k<<<(NPAD * DMODEL) / 256, 256, 0, stream>>>(in_proj, win, DINPROJ, DMODEL, NPAD * DMODEL);
    cvtpad_k<<<(DMODEL * DINNER) / 256, 256, 0, stream>>>(out_proj, wout, DMODEL, DINNER, DMODEL * DINNER);
    // 2) layernorm -> u bf16
    layernorm_k<<<MROWS, 256, 0, stream>>>(x, ln_w, ln_b, ubf);
    // 3) zxbcdt = u @ in_proj^T  (M=2048, N=8448, K=2048), fp32 out
    gemm_bt<0><<<dim3(NPAD / 128, MROWS / 128), 256, 0, stream>>>(ubf, win, zx, nullptr, MROWS, NPAD, DMODEL, DMODEL);
    // 4) conv + silu -> xin fp32, B/C fp32
    conv_k<<<(MROWS * CONVDIM + 255) / 256, 256, 0, stream>>>(zx, conv_w, conv_b, xin, bcf);
    // 5) dt / dA
    dt_k<<<(MROWS * NHEADS) / 256, 256, 0, stream>>>(zx, dt_bias, A_log, dtf, daf);
    // 6) scan (in-place xin -> y)
    scan_k<<<Bdim * NHEADS, 64, 0, stream>>>(xin, bcf, dtf, daf, Dp);
    // 7) gate + RMSNorm -> yg bf16 (strided into zx dead cols)
    gate_k<<<MROWS, 256, 0, stream>>>(xin, zx, norm_w, yg, ldyg);
    // 8) out = x + yg @ out_proj^T  (M=2048, N=2048, K=4096), fp32 out
    gemm_bt<1><<<dim3(DMODEL / 128, MROWS / 128), 256, 0, stream>>>(yg, wout, out, x, MROWS, DMODEL, DINNER, ldyg);
}

// Round 4
// 575.580 us; speedup vs baseline: 2.8249x; 2.8249x over previous
//
#include <hip/hip_runtime.h>
#include <hip/hip_bf16.h>

// ---------------- shapes ----------------
#define Bdim 2
#define Tdim 1024
#define DMODEL 2048
#define DSTATE 64
#define HEADDIM 64
#define DCONV 4
#define DINNER 4096
#define NHEADS 64
#define CONVDIM 4224           // DINNER + 2*DSTATE
#define DINPROJ 8384           // 2*DINNER + 2*DSTATE + NHEADS
#define NPAD 8448              // DINPROJ padded to multiple of 128
#define MROWS (Bdim*Tdim)      // 2048
#define QC 64                  // scan chunk length
#define NCHUNK (Tdim/QC)       // 16

typedef __attribute__((ext_vector_type(8))) short bf16x8;
typedef __attribute__((ext_vector_type(4))) float f32x4;

__device__ __forceinline__ unsigned short f2bf(float f) {
    unsigned int x = __builtin_bit_cast(unsigned int, f);
    x += 0x7fffu + ((x >> 16) & 1u);   // RNE
    return (unsigned short)(x >> 16);
}
__device__ __forceinline__ float bf2f(unsigned int u16) {
    unsigned int x = u16 << 16;
    return __builtin_bit_cast(float, x);
}
__device__ __forceinline__ float siluf(float v) {
    return v / (1.f + expf(-v));
}

// ---------------- fp32 -> bf16 weight convert (with zero row pad) ------------
__global__ __launch_bounds__(256) void cvtpad_k(const float* __restrict__ src,
                                                unsigned short* __restrict__ dst,
                                                int src_rows, int K, int total) {
    int idx = blockIdx.x * 256 + threadIdx.x;
    if (idx >= total) return;
    int row = idx / K;
    dst[idx] = (row < src_rows) ? f2bf(src[idx]) : (unsigned short)0;
}

// ---------------- LayerNorm: x fp32 -> u bf16 ----------------
__global__ __launch_bounds__(256) void layernorm_k(const float* __restrict__ x,
                                                   const float* __restrict__ w,
                                                   const float* __restrict__ b,
                                                   unsigned short* __restrict__ u) {
    int row = blockIdx.x;
    const float* xr = x + (size_t)row * DMODEL;
    float v[8];
    float s = 0.f, s2 = 0.f;
#pragma unroll
    for (int i = 0; i < 8; ++i) {
        v[i] = xr[threadIdx.x + 256 * i];
        s += v[i]; s2 += v[i] * v[i];
    }
#pragma unroll
    for (int off = 32; off; off >>= 1) { s += __shfl_down(s, off); s2 += __shfl_down(s2, off); }
    __shared__ float rs[4], rs2[4];
    if ((threadIdx.x & 63) == 0) { rs[threadIdx.x >> 6] = s; rs2[threadIdx.x >> 6] = s2; }
    __syncthreads();
    s = rs[0] + rs[1] + rs[2] + rs[3];
    s2 = rs2[0] + rs2[1] + rs2[2] + rs2[3];
    float mu = s * (1.f / DMODEL);
    float var = s2 * (1.f / DMODEL) - mu * mu;
    float inv = rsqrtf(var + 1e-5f);
#pragma unroll
    for (int i = 0; i < 8; ++i) {
        int c = threadIdx.x + 256 * i;
        float o = (v[i] - mu) * inv * w[c] + b[c];
        u[(size_t)row * DMODEL + c] = f2bf(o);
    }
}

// ---------------- bf16 GEMM, B given as (N x K) row-major ("B^T" form) -------
template <int EPI>
__global__ __launch_bounds__(256) void gemm_bt(const unsigned short* __restrict__ A,
                                               const unsigned short* __restrict__ Bw,
                                               float* __restrict__ Cout,
                                               const float* __restrict__ resid,
                                               int M, int N, int K, int lda) {
    const int m0 = blockIdx.y * 128, n0 = blockIdx.x * 128;
    __shared__ unsigned short As[128][40];
    __shared__ unsigned short Bs[128][40];
    const int tid = threadIdx.x;
    const int lane = tid & 63, w = tid >> 6;
    const int wm = (w >> 1) * 64, wn = (w & 1) * 64;
    const int r0 = tid >> 2, c0 = (tid & 3) * 8, r1 = r0 + 64;
    const int row16 = lane & 15, quad = lane >> 4, kq = quad * 8;

    f32x4 acc[4][4];
#pragma unroll
    for (int i = 0; i < 4; ++i)
#pragma unroll
        for (int j = 0; j < 4; ++j) acc[i][j] = (f32x4){0.f, 0.f, 0.f, 0.f};

    for (int k0 = 0; k0 < K; k0 += 32) {
        uint4 a0 = *(const uint4*)(A + (size_t)(m0 + r0) * lda + k0 + c0);
        uint4 a1 = *(const uint4*)(A + (size_t)(m0 + r1) * lda + k0 + c0);
        uint4 b0 = *(const uint4*)(Bw + (size_t)(n0 + r0) * K + k0 + c0);
        uint4 b1 = *(const uint4*)(Bw + (size_t)(n0 + r1) * K + k0 + c0);
        __syncthreads();
        *(uint4*)&As[r0][c0] = a0;
        *(uint4*)&As[r1][c0] = a1;
        *(uint4*)&Bs[r0][c0] = b0;
        *(uint4*)&Bs[r1][c0] = b1;
        __syncthreads();
        bf16x8 af[4], bfr[4];
#pragma unroll
        for (int i = 0; i < 4; ++i) af[i] = *(const bf16x8*)&As[wm + i * 16 + row16][kq];
#pragma unroll
        for (int j = 0; j < 4; ++j) bfr[j] = *(const bf16x8*)&Bs[wn + j * 16 + row16][kq];
#pragma unroll
        for (int i = 0; i < 4; ++i)
#pragma unroll
            for (int j = 0; j < 4; ++j)
                acc[i][j] = __builtin_amdgcn_mfma_f32_16x16x32_bf16(af[i], bfr[j], acc[i][j], 0, 0, 0);
    }

#pragma unroll
    for (int i = 0; i < 4; ++i)
#pragma unroll
        for (int j = 0; j < 4; ++j)
#pragma unroll
            for (int r = 0; r < 4; ++r) {
                int m = m0 + wm + i * 16 + quad * 4 + r;
                int n = n0 + wn + j * 16 + row16;
                float v = acc[i][j][r];
                if (EPI == 0)
                    Cout[(size_t)m * N + n] = v;
                else
                    Cout[(size_t)m * N + n] = resid[(size_t)m * N + n] + v;
            }
}

// ---------------- causal depthwise conv(4) + SiLU (fp32 in/out) --------------
__global__ __launch_bounds__(256) void conv_k(const float* __restrict__ zx,
                                              const float* __restrict__ cw,
                                              const float* __restrict__ cb,
                                              float* __restrict__ xin,
                                              float* __restrict__ bcf) {
    int idx = blockIdx.x * 256 + threadIdx.x;
    if (idx >= MROWS * CONVDIM) return;
    int c = idx % CONVDIM;
    int bt = idx / CONVDIM;
    int t = bt & (Tdim - 1);
    const float* base = zx + (size_t)bt * NPAD + DINNER + c;
    float acc = cb[c];
#pragma unroll
    for (int kk = 0; kk < DCONV; ++kk) {
        int tt = t - 3 + kk;
        if (tt >= 0) acc += base[(long)(kk - 3) * NPAD] * cw[c * 4 + kk];
    }
    float s = siluf(acc);
    if (c < DINNER) xin[(size_t)bt * DINNER + c] = s;
    else            bcf[(size_t)bt * 128 + (c - DINNER)] = s;
}

// -------- dt = softplus(dt_raw + bias); dtA = dt*A (log-decay per step) ------
__global__ __launch_bounds__(256) void dt_k(const float* __restrict__ zx,
                                            const float* __restrict__ dt_bias,
                                            const float* __restrict__ A_log,
                                            float* __restrict__ dtf,
                                            float* __restrict__ dtAf) {
    int idx = blockIdx.x * 256 + threadIdx.x;
    if (idx >= MROWS * NHEADS) return;
    int h = idx & 63;
    int bt = idx >> 6;
    float raw = zx[(size_t)bt * NPAD + (DINNER + CONVDIM) + h] + dt_bias[h];
    float dtv = (raw > 20.f) ? raw : log1pf(expf(raw));
    float A = -expf(A_log[h]);
    dtf[idx] = dtv;
    dtAf[idx] = dtv * A;     // <= 0
}

// ============ chunked SSM scan (SSD decomposition), Q=64 =====================
// Phase A: per (b,h,chunk): S[p][n] = sum_i exp(laQ - la_i) * dtx_i[p] * B_i[n]
__global__ __launch_bounds__(256) void chunk_state_k(const float* __restrict__ xin,
                                                     const float* __restrict__ bcf,
                                                     const float* __restrict__ dtf,
                                                     const float* __restrict__ dtAf,
                                                     float* __restrict__ Sst,
                                                     float* __restrict__ laq) {
    const int blk = blockIdx.x;
    const int c = blk & 15, h = (blk >> 4) & 63, b = blk >> 10;
    const int bt0 = b * Tdim + c * QC;
    const int tid = threadIdx.x;

    __shared__ float Bs[QC][68];
    __shared__ float Dx[QC][68];
    __shared__ float wsh[QC];

    if (tid < QC) {
        float v = dtAf[(bt0 + tid) * NHEADS + h];
#pragma unroll
        for (int d = 1; d < 64; d <<= 1) {
            float o = __shfl_up(v, d, 64);
            v += (tid >= d) ? o : 0.f;
        }
        float la63 = __shfl(v, 63, 64);
        wsh[tid] = expf(la63 - v);       // weight for step i
        if (tid == 63) laq[blk] = la63;  // chunk total log-decay
    }
    __syncthreads();

    const int row = tid >> 2, q = tid & 3;
    {
        float m = wsh[row] * dtf[(bt0 + row) * NHEADS + h];
        const float* xr = xin + (size_t)(bt0 + row) * DINNER + h * 64 + q * 16;
        const float* br = bcf + (size_t)(bt0 + row) * 128 + q * 16;
#pragma unroll
        for (int j = 0; j < 4; ++j) {
            float4 xv = *(const float4*)(xr + j * 4);
            float4 bv = *(const float4*)(br + j * 4);
            *(float4*)&Dx[row][q * 16 + j * 4] = (float4){m * xv.x, m * xv.y, m * xv.z, m * xv.w};
            *(float4*)&Bs[row][q * 16 + j * 4] = bv;
        }
    }
    __syncthreads();

    const int p0 = (tid >> 4) * 4, n0 = (tid & 15) * 4;
    float acc[4][4] = {};
    for (int i = 0; i < QC; ++i) {
        float4 dv = *(const float4*)&Dx[i][p0];
        float4 bv = *(const float4*)&Bs[i][n0];
        float dva[4] = {dv.x, dv.y, dv.z, dv.w};
        float bva[4] = {bv.x, bv.y, bv.z, bv.w};
#pragma unroll
        for (int a = 0; a < 4; ++a)
#pragma unroll
            for (int e = 0; e < 4; ++e) acc[a][e] += dva[a] * bva[e];
    }
    float* Sp = Sst + (size_t)blk * NPAD;
#pragma unroll
    for (int a = 0; a < 4; ++a)
        *(float4*)&Sp[(p0 + a) * 64 + n0] = (float4){acc[a][0], acc[a][1], acc[a][2], acc[a][3]};
}

// Phase B: per (b,h): running prefix of states across chunks (in place)
__global__ __launch_bounds__(256) void combine_k(float* __restrict__ Sst,
                                                 const float* __restrict__ laq) {
    const int bh = blockIdx.x;
    const int tid = threadIdx.x;
    float4 r0 = {}, r1 = {}, r2 = {}, r3 = {};
    for (int c = 0; c < NCHUNK - 1; ++c) {
        float* p = Sst + (size_t)(bh * 16 + c) * NPAD + tid * 16;
        float P = expf(laq[bh * 16 + c]);
        float4 s0 = ((const float4*)p)[0], s1 = ((const float4*)p)[1];
        float4 s2 = ((const float4*)p)[2], s3 = ((const float4*)p)[3];
        r0 = (float4){P * r0.x + s0.x, P * r0.y + s0.y, P * r0.z + s0.z, P * r0.w + s0.w};
        r1 = (float4){P * r1.x + s1.x, P * r1.y + s1.y, P * r1.z + s1.z, P * r1.w + s1.w};
        r2 = (float4){P * r2.x + s2.x, P * r2.y + s2.y, P * r2.z + s2.z, P * r2.w + s2.w};
        r3 = (float4){P * r3.x + s3.x, P * r3.y + s3.y, P * r3.z + s3.z, P * r3.w + s3.w};
        ((float4*)p)[0] = r0; ((float4*)p)[1] = r1;
        ((float4*)p)[2] = r2; ((float4*)p)[3] = r3;
    }
}

// Phase C: per (b,h,chunk): Y = (L.(C@B^T))@dtx + exp(la).(hinit@C^T) + D*x
// LDS kept under 64 KB (61,696 B): dtx tile staged as bf16.
__global__ __launch_bounds__(256) void chunk_out_k(float* __restrict__ xin,
                                                   const float* __restrict__ bcf,
                                                   const float* __restrict__ dtf,
                                                   const float* __restrict__ dtAf,
                                                   const float* __restrict__ Sst,
                                                   const float* __restrict__ Dp) {
    const int blk = blockIdx.x;
    const int c = blk & 15, h = (blk >> 4) & 63, b = blk >> 10;
    const int bt0 = b * Tdim + c * QC;
    const int tid = threadIdx.x;

    __shared__ float Cs[QC][68];             // [t][n]
    __shared__ float BsT[QC][68];            // [n][s]; later reused as hT [n][p]
    __shared__ unsigned short Dxh[QC][72];   // [s][p]  dt*x in bf16
    __shared__ float G[QC][68];              // [t][s]
    __shared__ float lash[QC];

    if (tid < QC) {
        float v = dtAf[(bt0 + tid) * NHEADS + h];
#pragma unroll
        for (int d = 1; d < 64; d <<= 1) {
            float o = __shfl_up(v, d, 64);
            v += (tid >= d) ? o : 0.f;
        }
        lash[tid] = v;
    }

    const int row = tid >> 2, q = tid & 3;
    {
        float m = dtf[(bt0 + row) * NHEADS + h];
        const float* xr = xin + (size_t)(bt0 + row) * DINNER + h * 64 + q * 16;
        const float* br = bcf + (size_t)(bt0 + row) * 128 + q * 16;        // B
        const float* cr = bcf + (size_t)(bt0 + row) * 128 + 64 + q * 16;   // C
#pragma unroll
        for (int j = 0; j < 4; ++j) {
            float4 xv = *(const float4*)(xr + j * 4);
            float4 bv = *(const float4*)(br + j * 4);
            float4 cv = *(const float4*)(cr + j * 4);
            unsigned int w0 = (unsigned int)f2bf(m * xv.x) | ((unsigned int)f2bf(m * xv.y) << 16);
            unsigned int w1 = (unsigned int)f2bf(m * xv.z) | ((unsigned int)f2bf(m * xv.w) << 16);
            *(uint2*)&Dxh[row][q * 16 + j * 4] = (uint2){w0, w1};
            *(float4*)&Cs[row][q * 16 + j * 4] = cv;
            int n = q * 16 + j * 4;
            BsT[n + 0][row] = bv.x; BsT[n + 1][row] = bv.y;
            BsT[n + 2][row] = bv.z; BsT[n + 3][row] = bv.w;
        }
    }
    __syncthreads();

    // ---- G = masked/decayed C @ B^T ----
    const int t0 = (tid >> 4) * 4, s0 = (tid & 15) * 4;
    {
        float acc[4][4] = {};
        for (int n = 0; n < 64; ++n) {
            float4 bv = *(const float4*)&BsT[n][s0];
            float bva[4] = {bv.x, bv.y, bv.z, bv.w};
            float cva[4] = {Cs[t0 + 0][n], Cs[t0 + 1][n], Cs[t0 + 2][n], Cs[t0 + 3][n]};
#pragma unroll
            for (int a = 0; a < 4; ++a)
#pragma unroll
                for (int e = 0; e < 4; ++e) acc[a][e] += cva[a] * bva[e];
        }
        float lat[4] = {lash[t0 + 0], lash[t0 + 1], lash[t0 + 2], lash[t0 + 3]};
#pragma unroll
        for (int a = 0; a < 4; ++a)
#pragma unroll
            for (int e = 0; e < 4; ++e) {
                int t = t0 + a, s = s0 + e;
                G[t][s] = (s <= t) ? acc[a][e] * expf(lat[a] - lash[s]) : 0.f;
            }
    }
    __syncthreads();

    // ---- load hinit (transposed) into BsT ----
    if (c > 0) {
        const float* Hp = Sst + (size_t)(blk - 1) * NPAD;   // slot c-1
#pragma unroll
        for (int j = 0; j < 4; ++j) {
            float4 hv = *(const float4*)&Hp[row * 64 + q * 16 + j * 4];
            int n = q * 16 + j * 4;
            BsT[n + 0][row] = hv.x; BsT[n + 1][row] = hv.y;
            BsT[n + 2][row] = hv.z; BsT[n + 3][row] = hv.w;   // hT[n][p]
        }
    }
    __syncthreads();

    // ---- Y ----
    const int p0 = (tid & 15) * 4;
    float accS[4][4] = {};
    for (int s = 0; s < 64; ++s) {
        uint2 dw = *(const uint2*)&Dxh[s][p0];
        float dva[4] = {bf2f(dw.x & 0xffffu), bf2f(dw.x >> 16),
                        bf2f(dw.y & 0xffffu), bf2f(dw.y >> 16)};
        float gva[4] = {G[t0 + 0][s], G[t0 + 1][s], G[t0 + 2][s], G[t0 + 3][s]};
#pragma unroll
        for (int a = 0; a < 4; ++a)
#pragma unroll
            for (int e = 0; e < 4; ++e) accS[a][e] += gva[a] * dva[e];
    }
    float accH[4][4] = {};
    if (c > 0) {
        for (int n = 0; n < 64; ++n) {
            float4 hv = *(const float4*)&BsT[n][p0];
            float hva[4] = {hv.x, hv.y, hv.z, hv.w};
            float cva[4] = {Cs[t0 + 0][n], Cs[t0 + 1][n], Cs[t0 + 2][n], Cs[t0 + 3][n]};
#pragma unroll
            for (int a = 0; a < 4; ++a)
#pragma unroll
                for (int e = 0; e < 4; ++e) accH[a][e] += cva[a] * hva[e];
        }
    }
    float Dh = Dp[h];
    float eA[4] = {expf(lash[t0 + 0]), expf(lash[t0 + 1]), expf(lash[t0 + 2]), expf(lash[t0 + 3])};
#pragma unroll
    for (int a = 0; a < 4; ++a) {
        float* xr = xin + (size_t)(bt0 + t0 + a) * DINNER + h * 64 + p0;
        float4 xv = *(const float4*)xr;
        float4 yv;
        yv.x = accS[a][0] + eA[a] * accH[a][0] + Dh * xv.x;
        yv.y = accS[a][1] + eA[a] * accH[a][1] + Dh * xv.y;
        yv.z = accS[a][2] + eA[a] * accH[a][2] + Dh * xv.z;
        yv.w = accS[a][3] + eA[a] * accH[a][3] + Dh * xv.w;
        *(float4*)xr = yv;
    }
}

// ---------------- y * silu(z), RMSNorm, -> bf16 (strided dest) ---------------
__global__ __launch_bounds__(256) void gate_k(const float* __restrict__ ybf,
                                              const float* __restrict__ zx,
                                              const float* __restrict__ nw,
                                              unsigned short* __restrict__ yg,
                                              int ldyg) {
    int row = blockIdx.x;
    float tv[16];
    float s2 = 0.f;
#pragma unroll
    for (int i = 0; i < 16; ++i) {
        int c = threadIdx.x + 256 * i;
        float y = ybf[(size_t)row * DINNER + c];
        float z = zx[(size_t)row * NPAD + c];
        float tvi = y * siluf(z);
        tv[i] = tvi;
        s2 += tvi * tvi;
    }
#pragma unroll
    for (int off = 32; off; off >>= 1) s2 += __shfl_down(s2, off);
    __shared__ float rs[4];
    if ((threadIdx.x & 63) == 0) rs[threadIdx.x >> 6] = s2;
    __syncthreads();
    s2 = rs[0] + rs[1] + rs[2] + rs[3];
    float scale = rsqrtf(s2 * (1.f / DINNER) + 1e-5f);
#pragma unroll
    for (int i = 0; i < 16; ++i) {
        int c = threadIdx.x + 256 * i;
        yg[(size_t)row * ldyg + c] = f2bf(tv[i] * scale * nw[c]);
    }
}

// ---------------- launch ----------------
extern "C" void kernel_launch(void* const* d_in, const int* in_sizes, int n_in,
                              void* d_out, int out_size, void* d_ws, size_t ws_size,
                              hipStream_t stream) {
    const float* x        = (const float*)d_in[0];
    const float* ln_w     = (const float*)d_in[1];
    const float* ln_b     = (const float*)d_in[2];
    const float* in_proj  = (const float*)d_in[3];
    const float* conv_w   = (const float*)d_in[4];
    const float* conv_b   = (const float*)d_in[5];
    const float* dt_bias  = (const float*)d_in[6];
    const float* A_log    = (const float*)d_in[7];
    const float* Dp       = (const float*)d_in[8];
    const float* norm_w   = (const float*)d_in[9];
    const float* out_proj = (const float*)d_in[10];
    float* out = (float*)d_out;
    char* ws = (char*)d_ws;

    // ---- workspace layout ----
    float*          zx   = (float*)(ws + 0);                   // 2048 x 8448 fp32
    unsigned short* wout = (unsigned short*)(ws + 69206016);
    unsigned short* win  = (unsigned short*)(ws + 85983232);
    unsigned short* ubf  = (unsigned short*)(ws + 120586240);
    float*          xin  = (float*)(ws + 85983232);            // reuses win after GEMM1
    float*          bcf  = (float*)(ws + 120586240);           // reuses ubf
    float*          dtf  = (float*)(ws + 121634816);
    float*          dtAf = (float*)(ws + 122159104);
    float*          laq  = (float*)(ws + 122683392);           // 2048 floats
    // S states live in dead xBC columns of zx: slot blk -> zx row blk, cols [4096,8192)
    float*          Sst  = zx + 4096;                          // row stride NPAD
    // yg bf16 packed into dead columns of zx (written AFTER scan completes)
    unsigned short* yg   = (unsigned short*)zx + 8192;
    const int       ldyg = 16896;

    cvtpad_k<<<(NPAD * DMODEL) / 256, 256, 0, stream>>>(in_proj, win, DINPROJ, DMODEL, NPAD * DMODEL);
    cvtpad_k<<<(DMODEL * DINNER) / 256, 256, 0, stream>>>(out_proj, wout, DMODEL, DINNER, DMODEL * DINNER);
    layernorm_k<<<MROWS, 256, 0, stream>>>(x, ln_w, ln_b, ubf);
    gemm_bt<0><<<dim3(NPAD / 128, MROWS / 128), 256, 0, stream>>>(ubf, win, zx, nullptr, MROWS, NPAD, DMODEL, DMODEL);
    conv_k<<<(MROWS * CONVDIM + 255) / 256, 256, 0, stream>>>(zx, conv_w, conv_b, xin, bcf);
    dt_k<<<(MROWS * NHEADS) / 256, 256, 0, stream>>>(zx, dt_bias, A_log, dtf, dtAf);
    // chunked scan
    chunk_state_k<<<Bdim * NHEADS * NCHUNK, 256, 0, stream>>>(xin, bcf, dtf, dtAf, Sst, laq);
    combine_k<<<Bdim * NHEADS, 256, 0, stream>>>(Sst, laq);
    chunk_out_k<<<Bdim * NHEADS * NCHUNK, 256, 0, stream>>>(xin, bcf, dtf, dtAf, Sst, Dp);
    // epilogue
    gate_k<<<MROWS, 256, 0, stream>>>(xin, zx, norm_w, yg, ldyg);
    gemm_bt<1><<<dim3(DMODEL / 128, MROWS / 128), 256, 0, stream>>>(yg, wout, out, x, MROWS, DMODEL, DINNER, ldyg);
}

// Round 5
// 559.544 us; speedup vs baseline: 2.9058x; 1.0287x over previous
//
#include <hip/hip_runtime.h>
#include <hip/hip_bf16.h>

// ---------------- shapes ----------------
#define Bdim 2
#define Tdim 1024
#define DMODEL 2048
#define DSTATE 64
#define HEADDIM 64
#define DCONV 4
#define DINNER 4096
#define NHEADS 64
#define CONVDIM 4224           // DINNER + 2*DSTATE
#define DINPROJ 8384           // 2*DINNER + 2*DSTATE + NHEADS
#define NPAD 8448              // DINPROJ padded to multiple of 128
#define MROWS (Bdim*Tdim)      // 2048
#define QC 64                  // scan chunk length
#define NCHUNK (Tdim/QC)       // 16

typedef __attribute__((ext_vector_type(8))) short bf16x8;
typedef __attribute__((ext_vector_type(4))) float f32x4;

#define GLB(p) ((const __attribute__((address_space(1))) void*)(p))
#define LDS(p) ((__attribute__((address_space(3))) void*)(p))

__device__ __forceinline__ unsigned short f2bf(float f) {
    unsigned int x = __builtin_bit_cast(unsigned int, f);
    x += 0x7fffu + ((x >> 16) & 1u);   // RNE
    return (unsigned short)(x >> 16);
}
__device__ __forceinline__ float bf2f(unsigned int u16) {
    unsigned int x = u16 << 16;
    return __builtin_bit_cast(float, x);
}
__device__ __forceinline__ float siluf(float v) {
    return v / (1.f + expf(-v));
}

// ---------------- fp32 -> bf16 weight convert (with zero row pad) ------------
__global__ __launch_bounds__(256) void cvtpad_k(const float* __restrict__ src,
                                                unsigned short* __restrict__ dst,
                                                int src_rows, int K, int total) {
    int idx = blockIdx.x * 256 + threadIdx.x;
    if (idx >= total) return;
    int row = idx / K;
    dst[idx] = (row < src_rows) ? f2bf(src[idx]) : (unsigned short)0;
}

// ---------------- LayerNorm: x fp32 -> u bf16 ----------------
__global__ __launch_bounds__(256) void layernorm_k(const float* __restrict__ x,
                                                   const float* __restrict__ w,
                                                   const float* __restrict__ b,
                                                   unsigned short* __restrict__ u) {
    int row = blockIdx.x;
    const float* xr = x + (size_t)row * DMODEL;
    float v[8];
    float s = 0.f, s2 = 0.f;
#pragma unroll
    for (int i = 0; i < 8; ++i) {
        v[i] = xr[threadIdx.x + 256 * i];
        s += v[i]; s2 += v[i] * v[i];
    }
#pragma unroll
    for (int off = 32; off; off >>= 1) { s += __shfl_down(s, off); s2 += __shfl_down(s2, off); }
    __shared__ float rs[4], rs2[4];
    if ((threadIdx.x & 63) == 0) { rs[threadIdx.x >> 6] = s; rs2[threadIdx.x >> 6] = s2; }
    __syncthreads();
    s = rs[0] + rs[1] + rs[2] + rs[3];
    s2 = rs2[0] + rs2[1] + rs2[2] + rs2[3];
    float mu = s * (1.f / DMODEL);
    float var = s2 * (1.f / DMODEL) - mu * mu;
    float inv = rsqrtf(var + 1e-5f);
#pragma unroll
    for (int i = 0; i < 8; ++i) {
        int c = threadIdx.x + 256 * i;
        float o = (v[i] - mu) * inv * w[c] + b[c];
        u[(size_t)row * DMODEL + c] = f2bf(o);
    }
}

// ---------------- bf16 GEMM, B given as (N x K) row-major ("B^T" form) -------
// m97-style staging: global_load_lds width=16 into unpadded 128x32 LDS tiles.
template <int EPI>
__global__ __launch_bounds__(256) void gemm_bt(const unsigned short* __restrict__ A,
                                               const unsigned short* __restrict__ Bw,
                                               float* __restrict__ Cout,
                                               const float* __restrict__ resid,
                                               int M, int N, int K, int lda) {
    const int m0 = blockIdx.y * 128, n0 = blockIdx.x * 128;
    __shared__ unsigned short As[128 * 32];   // 8 KB, row-major [row][0..31]
    __shared__ unsigned short Bs[128 * 32];
    const int tid = threadIdx.x;
    const int lane = tid & 63, w = tid >> 6;
    const int wm = (w >> 1) * 64, wn = (w & 1) * 64;
    const int r0 = tid >> 2, c0 = (tid & 3) * 8, r1 = r0 + 64;
    const int row16 = lane & 15, quad = lane >> 4, kq = quad * 8;

    const unsigned short* gA0 = A + (size_t)(m0 + r0) * lda + c0;
    const unsigned short* gA1 = A + (size_t)(m0 + r1) * lda + c0;
    const unsigned short* gB0 = Bw + (size_t)(n0 + r0) * K + c0;
    const unsigned short* gB1 = Bw + (size_t)(n0 + r1) * K + c0;

    f32x4 acc[4][4];
#pragma unroll
    for (int i = 0; i < 4; ++i)
#pragma unroll
        for (int j = 0; j < 4; ++j) acc[i][j] = (f32x4){0.f, 0.f, 0.f, 0.f};

    for (int k0 = 0; k0 < K; k0 += 32) {
        // async stage: LDS dest = wave-uniform base + lane*16 (layout == tid*16)
        __builtin_amdgcn_global_load_lds(GLB(gA0 + k0), LDS(As + tid * 8), 16, 0, 0);
        __builtin_amdgcn_global_load_lds(GLB(gA1 + k0), LDS(As + 2048 + tid * 8), 16, 0, 0);
        __builtin_amdgcn_global_load_lds(GLB(gB0 + k0), LDS(Bs + tid * 8), 16, 0, 0);
        __builtin_amdgcn_global_load_lds(GLB(gB1 + k0), LDS(Bs + 2048 + tid * 8), 16, 0, 0);
        __syncthreads();   // drains vmcnt -> staging complete

        bf16x8 af[4], bfr[4];
#pragma unroll
        for (int i = 0; i < 4; ++i) af[i] = *(const bf16x8*)&As[(wm + i * 16 + row16) * 32 + kq];
#pragma unroll
        for (int j = 0; j < 4; ++j) bfr[j] = *(const bf16x8*)&Bs[(wn + j * 16 + row16) * 32 + kq];
#pragma unroll
        for (int i = 0; i < 4; ++i)
#pragma unroll
            for (int j = 0; j < 4; ++j)
                acc[i][j] = __builtin_amdgcn_mfma_f32_16x16x32_bf16(af[i], bfr[j], acc[i][j], 0, 0, 0);
        __syncthreads();   // all reads done before next stage overwrites
    }

#pragma unroll
    for (int i = 0; i < 4; ++i)
#pragma unroll
        for (int j = 0; j < 4; ++j)
#pragma unroll
            for (int r = 0; r < 4; ++r) {
                int m = m0 + wm + i * 16 + quad * 4 + r;
                int n = n0 + wn + j * 16 + row16;
                float v = acc[i][j][r];
                if (EPI == 0)
                    Cout[(size_t)m * N + n] = v;
                else
                    Cout[(size_t)m * N + n] = resid[(size_t)m * N + n] + v;
            }
}

// ---------------- causal depthwise conv(4) + SiLU (fp32 in/out) --------------
__global__ __launch_bounds__(256) void conv_k(const float* __restrict__ zx,
                                              const float* __restrict__ cw,
                                              const float* __restrict__ cb,
                                              float* __restrict__ xin,
                                              float* __restrict__ bcf) {
    int idx = blockIdx.x * 256 + threadIdx.x;
    if (idx >= MROWS * CONVDIM) return;
    int c = idx % CONVDIM;
    int bt = idx / CONVDIM;
    int t = bt & (Tdim - 1);
    const float* base = zx + (size_t)bt * NPAD + DINNER + c;
    float acc = cb[c];
#pragma unroll
    for (int kk = 0; kk < DCONV; ++kk) {
        int tt = t - 3 + kk;
        if (tt >= 0) acc += base[(long)(kk - 3) * NPAD] * cw[c * 4 + kk];
    }
    float s = siluf(acc);
    if (c < DINNER) xin[(size_t)bt * DINNER + c] = s;
    else            bcf[(size_t)bt * 128 + (c - DINNER)] = s;
}

// -------- dt = softplus(dt_raw + bias); dtA = dt*A (log-decay per step) ------
__global__ __launch_bounds__(256) void dt_k(const float* __restrict__ zx,
                                            const float* __restrict__ dt_bias,
                                            const float* __restrict__ A_log,
                                            float* __restrict__ dtf,
                                            float* __restrict__ dtAf) {
    int idx = blockIdx.x * 256 + threadIdx.x;
    if (idx >= MROWS * NHEADS) return;
    int h = idx & 63;
    int bt = idx >> 6;
    float raw = zx[(size_t)bt * NPAD + (DINNER + CONVDIM) + h] + dt_bias[h];
    float dtv = (raw > 20.f) ? raw : log1pf(expf(raw));
    float A = -expf(A_log[h]);
    dtf[idx] = dtv;
    dtAf[idx] = dtv * A;     // <= 0
}

// ============ chunked SSM scan (SSD decomposition), Q=64 =====================
// Phase A: per (b,h,chunk): S[p][n] = sum_i exp(laQ - la_i) * dtx_i[p] * B_i[n]
__global__ __launch_bounds__(256) void chunk_state_k(const float* __restrict__ xin,
                                                     const float* __restrict__ bcf,
                                                     const float* __restrict__ dtf,
                                                     const float* __restrict__ dtAf,
                                                     float* __restrict__ Sst,
                                                     float* __restrict__ laq) {
    const int blk = blockIdx.x;
    const int c = blk & 15, h = (blk >> 4) & 63, b = blk >> 10;
    const int bt0 = b * Tdim + c * QC;
    const int tid = threadIdx.x;

    __shared__ float Bs[QC][68];
    __shared__ float Dx[QC][68];
    __shared__ float wsh[QC];

    if (tid < QC) {
        float v = dtAf[(bt0 + tid) * NHEADS + h];
#pragma unroll
        for (int d = 1; d < 64; d <<= 1) {
            float o = __shfl_up(v, d, 64);
            v += (tid >= d) ? o : 0.f;
        }
        float la63 = __shfl(v, 63, 64);
        wsh[tid] = expf(la63 - v);       // weight for step i
        if (tid == 63) laq[blk] = la63;  // chunk total log-decay
    }
    __syncthreads();

    const int row = tid >> 2, q = tid & 3;
    {
        float m = wsh[row] * dtf[(bt0 + row) * NHEADS + h];
        const float* xr = xin + (size_t)(bt0 + row) * DINNER + h * 64 + q * 16;
        const float* br = bcf + (size_t)(bt0 + row) * 128 + q * 16;
#pragma unroll
        for (int j = 0; j < 4; ++j) {
            float4 xv = *(const float4*)(xr + j * 4);
            float4 bv = *(const float4*)(br + j * 4);
            *(float4*)&Dx[row][q * 16 + j * 4] = (float4){m * xv.x, m * xv.y, m * xv.z, m * xv.w};
            *(float4*)&Bs[row][q * 16 + j * 4] = bv;
        }
    }
    __syncthreads();

    const int p0 = (tid >> 4) * 4, n0 = (tid & 15) * 4;
    float acc[4][4] = {};
    for (int i = 0; i < QC; ++i) {
        float4 dv = *(const float4*)&Dx[i][p0];
        float4 bv = *(const float4*)&Bs[i][n0];
        float dva[4] = {dv.x, dv.y, dv.z, dv.w};
        float bva[4] = {bv.x, bv.y, bv.z, bv.w};
#pragma unroll
        for (int a = 0; a < 4; ++a)
#pragma unroll
            for (int e = 0; e < 4; ++e) acc[a][e] += dva[a] * bva[e];
    }
    float* Sp = Sst + (size_t)blk * NPAD;
#pragma unroll
    for (int a = 0; a < 4; ++a)
        *(float4*)&Sp[(p0 + a) * 64 + n0] = (float4){acc[a][0], acc[a][1], acc[a][2], acc[a][3]};
}

// Phase B: per (b,h): running prefix of states across chunks (in place)
__global__ __launch_bounds__(256) void combine_k(float* __restrict__ Sst,
                                                 const float* __restrict__ laq) {
    const int bh = blockIdx.x;
    const int tid = threadIdx.x;
    float4 r0 = {}, r1 = {}, r2 = {}, r3 = {};
    for (int c = 0; c < NCHUNK - 1; ++c) {
        float* p = Sst + (size_t)(bh * 16 + c) * NPAD + tid * 16;
        float P = expf(laq[bh * 16 + c]);
        float4 s0 = ((const float4*)p)[0], s1 = ((const float4*)p)[1];
        float4 s2 = ((const float4*)p)[2], s3 = ((const float4*)p)[3];
        r0 = (float4){P * r0.x + s0.x, P * r0.y + s0.y, P * r0.z + s0.z, P * r0.w + s0.w};
        r1 = (float4){P * r1.x + s1.x, P * r1.y + s1.y, P * r1.z + s1.z, P * r1.w + s1.w};
        r2 = (float4){P * r2.x + s2.x, P * r2.y + s2.y, P * r2.z + s2.z, P * r2.w + s2.w};
        r3 = (float4){P * r3.x + s3.x, P * r3.y + s3.y, P * r3.z + s3.z, P * r3.w + s3.w};
        ((float4*)p)[0] = r0; ((float4*)p)[1] = r1;
        ((float4*)p)[2] = r2; ((float4*)p)[3] = r3;
    }
}

// Phase C: per (b,h,chunk): Y = (L.(C@B^T))@dtx + exp(la).(hinit@C^T) + D*x
// LDS kept under 64 KB (61,696 B): dtx tile staged as bf16.
__global__ __launch_bounds__(256) void chunk_out_k(float* __restrict__ xin,
                                                   const float* __restrict__ bcf,
                                                   const float* __restrict__ dtf,
                                                   const float* __restrict__ dtAf,
                                                   const float* __restrict__ Sst,
                                                   const float* __restrict__ Dp) {
    const int blk = blockIdx.x;
    const int c = blk & 15, h = (blk >> 4) & 63, b = blk >> 10;
    const int bt0 = b * Tdim + c * QC;
    const int tid = threadIdx.x;

    __shared__ float Cs[QC][68];             // [t][n]
    __shared__ float BsT[QC][68];            // [n][s]; later reused as hT [n][p]
    __shared__ unsigned short Dxh[QC][72];   // [s][p]  dt*x in bf16
    __shared__ float G[QC][68];              // [t][s]
    __shared__ float lash[QC];

    if (tid < QC) {
        float v = dtAf[(bt0 + tid) * NHEADS + h];
#pragma unroll
        for (int d = 1; d < 64; d <<= 1) {
            float o = __shfl_up(v, d, 64);
            v += (tid >= d) ? o : 0.f;
        }
        lash[tid] = v;
    }

    const int row = tid >> 2, q = tid & 3;
    {
        float m = dtf[(bt0 + row) * NHEADS + h];
        const float* xr = xin + (size_t)(bt0 + row) * DINNER + h * 64 + q * 16;
        const float* br = bcf + (size_t)(bt0 + row) * 128 + q * 16;        // B
        const float* cr = bcf + (size_t)(bt0 + row) * 128 + 64 + q * 16;   // C
#pragma unroll
        for (int j = 0; j < 4; ++j) {
            float4 xv = *(const float4*)(xr + j * 4);
            float4 bv = *(const float4*)(br + j * 4);
            float4 cv = *(const float4*)(cr + j * 4);
            unsigned int w0 = (unsigned int)f2bf(m * xv.x) | ((unsigned int)f2bf(m * xv.y) << 16);
            unsigned int w1 = (unsigned int)f2bf(m * xv.z) | ((unsigned int)f2bf(m * xv.w) << 16);
            *(uint2*)&Dxh[row][q * 16 + j * 4] = (uint2){w0, w1};
            *(float4*)&Cs[row][q * 16 + j * 4] = cv;
            int n = q * 16 + j * 4;
            BsT[n + 0][row] = bv.x; BsT[n + 1][row] = bv.y;
            BsT[n + 2][row] = bv.z; BsT[n + 3][row] = bv.w;
        }
    }
    __syncthreads();

    // ---- G = masked/decayed C @ B^T ----
    const int t0 = (tid >> 4) * 4, s0 = (tid & 15) * 4;
    {
        float acc[4][4] = {};
        for (int n = 0; n < 64; ++n) {
            float4 bv = *(const float4*)&BsT[n][s0];
            float bva[4] = {bv.x, bv.y, bv.z, bv.w};
            float cva[4] = {Cs[t0 + 0][n], Cs[t0 + 1][n], Cs[t0 + 2][n], Cs[t0 + 3][n]};
#pragma unroll
            for (int a = 0; a < 4; ++a)
#pragma unroll
                for (int e = 0; e < 4; ++e) acc[a][e] += cva[a] * bva[e];
        }
        float lat[4] = {lash[t0 + 0], lash[t0 + 1], lash[t0 + 2], lash[t0 + 3]};
#pragma unroll
        for (int a = 0; a < 4; ++a)
#pragma unroll
            for (int e = 0; e < 4; ++e) {
                int t = t0 + a, s = s0 + e;
                G[t][s] = (s <= t) ? acc[a][e] * expf(lat[a] - lash[s]) : 0.f;
            }
    }
    __syncthreads();

    // ---- load hinit (transposed) into BsT ----
    if (c > 0) {
        const float* Hp = Sst + (size_t)(blk - 1) * NPAD;   // slot c-1
#pragma unroll
        for (int j = 0; j < 4; ++j) {
            float4 hv = *(const float4*)&Hp[row * 64 + q * 16 + j * 4];
            int n = q * 16 + j * 4;
            BsT[n + 0][row] = hv.x; BsT[n + 1][row] = hv.y;
            BsT[n + 2][row] = hv.z; BsT[n + 3][row] = hv.w;   // hT[n][p]
        }
    }
    __syncthreads();

    // ---- Y ----
    const int p0 = (tid & 15) * 4;
    float accS[4][4] = {};
    for (int s = 0; s < 64; ++s) {
        uint2 dw = *(const uint2*)&Dxh[s][p0];
        float dva[4] = {bf2f(dw.x & 0xffffu), bf2f(dw.x >> 16),
                        bf2f(dw.y & 0xffffu), bf2f(dw.y >> 16)};
        float gva[4] = {G[t0 + 0][s], G[t0 + 1][s], G[t0 + 2][s], G[t0 + 3][s]};
#pragma unroll
        for (int a = 0; a < 4; ++a)
#pragma unroll
            for (int e = 0; e < 4; ++e) accS[a][e] += gva[a] * dva[e];
    }
    float accH[4][4] = {};
    if (c > 0) {
        for (int n = 0; n < 64; ++n) {
            float4 hv = *(const float4*)&BsT[n][p0];
            float hva[4] = {hv.x, hv.y, hv.z, hv.w};
            float cva[4] = {Cs[t0 + 0][n], Cs[t0 + 1][n], Cs[t0 + 2][n], Cs[t0 + 3][n]};
#pragma unroll
            for (int a = 0; a < 4; ++a)
#pragma unroll
                for (int e = 0; e < 4; ++e) accH[a][e] += cva[a] * hva[e];
        }
    }
    float Dh = Dp[h];
    float eA[4] = {expf(lash[t0 + 0]), expf(lash[t0 + 1]), expf(lash[t0 + 2]), expf(lash[t0 + 3])};
#pragma unroll
    for (int a = 0; a < 4; ++a) {
        float* xr = xin + (size_t)(bt0 + t0 + a) * DINNER + h * 64 + p0;
        float4 xv = *(const float4*)xr;
        float4 yv;
        yv.x = accS[a][0] + eA[a] * accH[a][0] + Dh * xv.x;
        yv.y = accS[a][1] + eA[a] * accH[a][1] + Dh * xv.y;
        yv.z = accS[a][2] + eA[a] * accH[a][2] + Dh * xv.z;
        yv.w = accS[a][3] + eA[a] * accH[a][3] + Dh * xv.w;
        *(float4*)xr = yv;
    }
}

// ---------------- y * silu(z), RMSNorm, -> bf16 (strided dest) ---------------
__global__ __launch_bounds__(256) void gate_k(const float* __restrict__ ybf,
                                              const float* __restrict__ zx,
                                              const float* __restrict__ nw,
                                              unsigned short* __restrict__ yg,
                                              int ldyg) {
    int row = blockIdx.x;
    float tv[16];
    float s2 = 0.f;
#pragma unroll
    for (int i = 0; i < 16; ++i) {
        int c = threadIdx.x + 256 * i;
        float y = ybf[(size_t)row * DINNER + c];
        float z = zx[(size_t)row * NPAD + c];
        float tvi = y * siluf(z);
        tv[i] = tvi;
        s2 += tvi * tvi;
    }
#pragma unroll
    for (int off = 32; off; off >>= 1) s2 += __shfl_down(s2, off);
    __shared__ float rs[4];
    if ((threadIdx.x & 63) == 0) rs[threadIdx.x >> 6] = s2;
    __syncthreads();
    s2 = rs[0] + rs[1] + rs[2] + rs[3];
    float scale = rsqrtf(s2 * (1.f / DINNER) + 1e-5f);
#pragma unroll
    for (int i = 0; i < 16; ++i) {
        int c = threadIdx.x + 256 * i;
        yg[(size_t)row * ldyg + c] = f2bf(tv[i] * scale * nw[c]);
    }
}

// ---------------- launch ----------------
extern "C" void kernel_launch(void* const* d_in, const int* in_sizes, int n_in,
                              void* d_out, int out_size, void* d_ws, size_t ws_size,
                              hipStream_t stream) {
    const float* x        = (const float*)d_in[0];
    const float* ln_w     = (const float*)d_in[1];
    const float* ln_b     = (const float*)d_in[2];
    const float* in_proj  = (const float*)d_in[3];
    const float* conv_w   = (const float*)d_in[4];
    const float* conv_b   = (const float*)d_in[5];
    const float* dt_bias  = (const float*)d_in[6];
    const float* A_log    = (const float*)d_in[7];
    const float* Dp       = (const float*)d_in[8];
    const float* norm_w   = (const float*)d_in[9];
    const float* out_proj = (const float*)d_in[10];
    float* out = (float*)d_out;
    char* ws = (char*)d_ws;

    // ---- workspace layout ----
    float*          zx   = (float*)(ws + 0);                   // 2048 x 8448 fp32
    unsigned short* wout = (unsigned short*)(ws + 69206016);
    unsigned short* win  = (unsigned short*)(ws + 85983232);
    unsigned short* ubf  = (unsigned short*)(ws + 120586240);
    float*          xin  = (float*)(ws + 85983232);            // reuses win after GEMM1
    float*          bcf  = (float*)(ws + 120586240);           // reuses ubf
    float*          dtf  = (float*)(ws + 121634816);
    float*          dtAf = (float*)(ws + 122159104);
    float*          laq  = (float*)(ws + 122683392);           // 2048 floats
    // S states live in dead xBC columns of zx: slot blk -> zx row blk, cols [4096,8192)
    float*          Sst  = zx + 4096;                          // row stride NPAD
    // yg bf16 packed into dead columns of zx (written AFTER scan completes)
    unsigned short* yg   = (unsigned short*)zx + 8192;
    const int       ldyg = 16896;

    cvtpad_k<<<(NPAD * DMODEL) / 256, 256, 0, stream>>>(in_proj, win, DINPROJ, DMODEL, NPAD * DMODEL);
    cvtpad_k<<<(DMODEL * DINNER) / 256, 256, 0, stream>>>(out_proj, wout, DMODEL, DINNER, DMODEL * DINNER);
    layernorm_k<<<MROWS, 256, 0, stream>>>(x, ln_w, ln_b, ubf);
    gemm_bt<0><<<dim3(NPAD / 128, MROWS / 128), 256, 0, stream>>>(ubf, win, zx, nullptr, MROWS, NPAD, DMODEL, DMODEL);
    conv_k<<<(MROWS * CONVDIM + 255) / 256, 256, 0, stream>>>(zx, conv_w, conv_b, xin, bcf);
    dt_k<<<(MROWS * NHEADS) / 256, 256, 0, stream>>>(zx, dt_bias, A_log, dtf, dtAf);
    // chunked scan
    chunk_state_k<<<Bdim * NHEADS * NCHUNK, 256, 0, stream>>>(xin, bcf, dtf, dtAf, Sst, laq);
    combine_k<<<Bdim * NHEADS, 256, 0, stream>>>(Sst, laq);
    chunk_out_k<<<Bdim * NHEADS * NCHUNK, 256, 0, stream>>>(xin, bcf, dtf, dtAf, Sst, Dp);
    // epilogue
    gate_k<<<MROWS, 256, 0, stream>>>(xin, zx, norm_w, yg, ldyg);
    gemm_bt<1><<<dim3(DMODEL / 128, MROWS / 128), 256, 0, stream>>>(yg, wout, out, x, MROWS, DMODEL, DINNER, ldyg);
}